// Round 2
// baseline (3419.555 us; speedup 1.0000x reference)
//
#include <hip/hip_runtime.h>
#include <cstdint>

// Problem constants
#define DIMV   256
#define DINNER 512
#define STATE  64

static __device__ __forceinline__ float sigmoidf_(float x){ return 1.f/(1.f+expf(-x)); }
static __device__ __forceinline__ float siluf_(float x){ return x/(1.f+expf(-x)); }
static __device__ __forceinline__ float softplusf_(float x){
    return fmaxf(x,0.f) + log1pf(expf(-fabsf(x)));
}

// ---------------------------------------------------------------------------
// prep: build interleaved sequences for one bicms into xbuf (both stacks get
// the same initial tokens; bwd is handled by reverse-order scan, not a flip).
// bi==0: horizontal, Bs=128 (b*32+r), Lint=128, token t=2w+m
// bi==1: vertical,   Bs=256 (b*64+w), Lint=64,  token t=2h+m
// ---------------------------------------------------------------------------
__global__ __launch_bounds__(64) void prep_k(const float* __restrict__ sem,
                                             const float* __restrict__ inst,
                                             float* __restrict__ xbuf, int bi)
{
    int u = blockIdx.x;          // 0..16383 token within stack
    int lane = threadIdx.x;      // 0..63, 4 floats each
    int t; long n;
    if (bi == 0) {
        int s = u >> 7; t = u & 127;
        int b = s >> 5, r = s & 31; int w = t >> 1;
        n = (long)b*2048 + r*64 + w;
    } else {
        int s = u >> 6; t = u & 63;
        int b = s >> 6, w = s & 63; int hh = t >> 1;
        n = (long)b*2048 + hh*64 + w;
    }
    const float* src = ((t & 1) ? inst : sem) + n*256 + lane*4;
    float4 v = *(const float4*)src;
    *(float4*)(xbuf + (long)u*256 + lane*4) = v;
    *(float4*)(xbuf + ((long)16384 + u)*256 + lane*4) = v;
}

// ---------------------------------------------------------------------------
// LayerNorm over 256 dims, one wave (64 lanes) per token, float4 per lane.
// z = tok / tokensPerZ selects per-stack params (pStride elements apart).
// ---------------------------------------------------------------------------
__global__ __launch_bounds__(64) void ln_k(const float* __restrict__ x,
                                           float* __restrict__ out,
                                           const float* __restrict__ sp,
                                           const float* __restrict__ bp,
                                           int pStride, int tokensPerZ)
{
    long tok = blockIdx.x;
    int z = (int)(tok / tokensPerZ);
    const float* s = sp + (long)z*pStride;
    const float* b = bp + (long)z*pStride;
    int lane = threadIdx.x;
    float4 v = *(const float4*)(x + tok*256 + lane*4);
    float sum = v.x+v.y+v.z+v.w;
    #pragma unroll
    for (int o=32;o>=1;o>>=1) sum += __shfl_xor(sum,o);
    float mu = sum * (1.f/256.f);
    float cx=v.x-mu, cy=v.y-mu, cz=v.z-mu, cw=v.w-mu;
    float vs = cx*cx+cy*cy+cz*cz+cw*cw;
    #pragma unroll
    for (int o=32;o>=1;o>>=1) vs += __shfl_xor(vs,o);
    float r = rsqrtf(vs*(1.f/256.f) + 1e-5f);
    float4 sv = *(const float4*)(s + lane*4);
    float4 bv = *(const float4*)(b + lane*4);
    float4 o4;
    o4.x = cx*r*sv.x + bv.x;
    o4.y = cy*r*sv.y + bv.y;
    o4.z = cz*r*sv.z + bv.z;
    o4.w = cw*r*sv.w + bv.w;
    *(float4*)(out + tok*256 + lane*4) = o4;
}

// ---------------------------------------------------------------------------
// Generic fp32 tiled GEMM: C[z] = epilogue( A[z] @ W[z] )
//   A rows: token-major, row stride lda; split-A for K>splitK (gate concat).
//   W: K x N row-major, per-z stride wStride.
// Epilogue modes fuse all elementwise ops of the network.
// 64x64 tile, BK=16, 256 threads, 4x4 micro-tile.
// ---------------------------------------------------------------------------
#define BM 64
#define BN 64
#define BK 16
enum { EPI_PLAIN=0, EPI_SILU=1, EPI_SOFTPLUS=2, EPI_ZGATE=3, EPI_RESID=4, EPI_GATE=5, EPI_BIAS=6 };

__global__ __launch_bounds__(256) void gemm_k(
    const float* __restrict__ A, const float* __restrict__ A2, int splitK, int lda,
    const float* __restrict__ Wb, long wStride,
    float* __restrict__ Cout,
    int M, int K, int N, int mode,
    const float* __restrict__ p1, long s1,
    const float* __restrict__ p2, long s2,
    const float* __restrict__ p3, long s3)
{
    __shared__ float As[BK][BM+4];
    __shared__ float Ws[BK][BN+4];
    int z = blockIdx.z;
    const float* Az  = A  + (long)z*M*lda;
    const float* A2z = A2 ? (A2 + (long)z*M*lda) : (const float*)0;
    const float* Wz  = Wb + (long)z*wStride;
    int bm = blockIdx.x * BM;
    int bn = blockIdx.y * BN;
    int tid = threadIdx.x;
    int tx = tid & 15, ty = tid >> 4;

    float acc[4][4] = {};
    for (int k0 = 0; k0 < K; k0 += BK) {
        const float* Ab; int kl;
        if (k0 < splitK) { Ab = Az; kl = k0; } else { Ab = A2z; kl = k0 - splitK; }
        #pragma unroll
        for (int i = 0; i < 4; i++) {
            int idx = tid + i*256;
            int r = idx >> 4, c = idx & 15;
            As[c][r] = Ab[(long)(bm + r)*lda + (kl + c)];
        }
        #pragma unroll
        for (int i = 0; i < 4; i++) {
            int idx = tid + i*256;
            int r = idx >> 6, c = idx & 63;
            Ws[r][c] = Wz[(long)(k0 + r)*N + (bn + c)];
        }
        __syncthreads();
        #pragma unroll
        for (int kk = 0; kk < BK; kk++) {
            float4 av = *(const float4*)&As[kk][ty*4];
            float4 wv = *(const float4*)&Ws[kk][tx*4];
            float a4[4] = {av.x, av.y, av.z, av.w};
            float w4[4] = {wv.x, wv.y, wv.z, wv.w};
            #pragma unroll
            for (int i=0;i<4;i++)
                #pragma unroll
                for (int j=0;j<4;j++)
                    acc[i][j] = fmaf(a4[i], w4[j], acc[i][j]);
        }
        __syncthreads();
    }
    #pragma unroll
    for (int i=0;i<4;i++){
        int row = bm + ty*4 + i;
        #pragma unroll
        for (int j=0;j<4;j++){
            int col = bn + tx*4 + j;
            long rc = ((long)z*M + row)*N + col;
            float v = acc[i][j];
            float o;
            if (mode == EPI_PLAIN)        o = v;
            else if (mode == EPI_SILU)    o = siluf_(v);
            else if (mode == EPI_SOFTPLUS)o = softplusf_(v + p1[(long)z*s1 + col]);
            else if (mode == EPI_ZGATE) { // (y + Dskip*xs) * silu(z_proj); overwrite y
                float yv = p1[rc], xv = p2[rc], dsk = p3[(long)z*s3 + col];
                o = (yv + dsk*xv) * siluf_(v);
            }
            else if (mode == EPI_RESID)   o = p1[rc] + v;     // x += g @ Wout
            else if (mode == EPI_GATE) {  // sigmoid gate merge of fwd/bwd
                float g = sigmoidf_(v + p3[col]);
                long rl = (long)row*N + col;
                o = g*p1[rl] + (1.f-g)*p2[rl];
            }
            else /*EPI_BIAS*/             o = v + p1[col];
            Cout[rc] = o;
        }
    }
}

// ---------------------------------------------------------------------------
// Selective scan. grid.x = 2*Bs (stack 0 fwd, stack 1 bwd/reverse),
// grid.y = 2 (channel halves), 256 threads = 256 channels.
// One thread owns hs[64] in registers; B/C staged in LDS per step.
// y may alias dt: each (tok,d) is read (dt) before written (y) by the
// same thread, and no other block touches that (tok,d).
// ---------------------------------------------------------------------------
__global__ __launch_bounds__(256) void scan_k(
    const float* __restrict__ dt, const float* __restrict__ xs,
    const float* __restrict__ Bm, const float* __restrict__ Cm,
    const float* __restrict__ Alog, long aStride,
    float* __restrict__ y, int Bs, int Lint)
{
    int q = blockIdx.x;
    int stack = q / Bs;
    int seq = q - stack*Bs;
    int d = blockIdx.y*256 + threadIdx.x;
    float Ad = -expf(Alog[(long)stack*aStride + d]);
    long stackOff = (long)stack * 16384;   // tokens per stack (Bs*Lint == 16384 for both bicms)
    __shared__ float Bsh[STATE], Csh[STATE];
    float hs[STATE];
    #pragma unroll
    for (int s=0;s<STATE;s++) hs[s] = 0.f;
    for (int it=0; it<Lint; ++it) {
        int t = stack ? (Lint-1-it) : it;
        long tok = stackOff + (long)seq*Lint + t;
        if (threadIdx.x < STATE)          Bsh[threadIdx.x]        = Bm[tok*STATE + threadIdx.x];
        else if (threadIdx.x < 2*STATE)   Csh[threadIdx.x-STATE]  = Cm[tok*STATE + threadIdx.x - STATE];
        __syncthreads();
        float dv = dt[tok*DINNER + d];
        float xv = xs[tok*DINNER + d];
        float w  = expf(dv * Ad);
        float u  = dv * xv;
        float acc = 0.f;
        const float4* B4 = (const float4*)Bsh;
        const float4* C4 = (const float4*)Csh;
        #pragma unroll
        for (int s4=0; s4<STATE/4; ++s4) {
            float4 bv = B4[s4], cv = C4[s4];
            int s0 = 4*s4;
            hs[s0+0] = fmaf(w, hs[s0+0], u*bv.x); acc = fmaf(hs[s0+0], cv.x, acc);
            hs[s0+1] = fmaf(w, hs[s0+1], u*bv.y); acc = fmaf(hs[s0+1], cv.y, acc);
            hs[s0+2] = fmaf(w, hs[s0+2], u*bv.z); acc = fmaf(hs[s0+2], cv.z, acc);
            hs[s0+3] = fmaf(w, hs[s0+3], u*bv.w); acc = fmaf(hs[s0+3], cv.w, acc);
        }
        y[tok*DINNER + d] = acc;
        __syncthreads();
    }
}

// ---------------------------------------------------------------------------
// Gather merged_h / merged_v rows into contiguous concat buffers for the
// final merge GEMMs. n = b*2048 + r*64 + w.
// ---------------------------------------------------------------------------
__global__ __launch_bounds__(64) void gather_k(const float* __restrict__ mh,
                                               const float* __restrict__ mv,
                                               float* __restrict__ catsem,
                                               float* __restrict__ catinst)
{
    int n = blockIdx.x;            // 0..8191
    int lane = threadIdx.x;
    int b = n >> 11;
    int rem = n & 2047;
    int r = rem >> 6, w = rem & 63;
    long hrow = ((long)(b*32 + r)*128 + 2*w)*256;
    long vrow = ((long)(b*64 + w)*64  + 2*r)*256;
    float4 hsv = *(const float4*)(mh + hrow + lane*4);
    float4 vsv = *(const float4*)(mv + vrow + lane*4);
    float4 hiv = *(const float4*)(mh + hrow + 256 + lane*4);
    float4 viv = *(const float4*)(mv + vrow + 256 + lane*4);
    *(float4*)(catsem  + (long)n*512 +       lane*4) = hsv;
    *(float4*)(catsem  + (long)n*512 + 256 + lane*4) = vsv;
    *(float4*)(catinst + (long)n*512 +       lane*4) = hiv;
    *(float4*)(catinst + (long)n*512 + 256 + lane*4) = viv;
}

// ---------------------------------------------------------------------------
extern "C" void kernel_launch(void* const* d_in, const int* in_sizes, int n_in,
                              void* d_out, int out_size, void* d_ws, size_t ws_size,
                              hipStream_t stream)
{
    (void)in_sizes; (void)n_in; (void)out_size; (void)ws_size;
    const float* sem  = (const float*)d_in[0];
    const float* inst = (const float*)d_in[1];
    const float* Wx   = (const float*)d_in[2];
    const float* Wz   = (const float*)d_in[3];
    const float* Wdt  = (const float*)d_in[4];
    const float* WB   = (const float*)d_in[5];
    const float* WC   = (const float*)d_in[6];
    const float* Alog = (const float*)d_in[7];
    const float* Dsk  = (const float*)d_in[8];
    const float* dtb  = (const float*)d_in[9];
    const float* Wo   = (const float*)d_in[10];
    const float* lns  = (const float*)d_in[11];
    const float* lnb  = (const float*)d_in[12];
    const float* gW   = (const float*)d_in[13];
    const float* gb   = (const float*)d_in[14];
    const float* mW   = (const float*)d_in[15];
    const float* mb   = (const float*)d_in[16];
    const float* mlns = (const float*)d_in[17];
    const float* mlnb = (const float*)d_in[18];
    float* out = (float*)d_out;

    // workspace layout (floats) — total 62,914,560 floats = 240 MiB
    float* ws   = (float*)d_ws;
    const long T2 = 32768;                      // tokens per bicms (2 stacks x 16384)
    float* xbuf = ws;                           // T2*256  = 8,388,608
    float* hbuf = xbuf  + T2*256;               // T2*256  = 8,388,608
    float* xsb  = hbuf  + T2*256;               // T2*512  = 16,777,216
    float* ydt  = xsb   + T2*512;               // T2*512  = 16,777,216 (dt, then y in-place, then logits)
    float* Bb   = ydt   + T2*512;               // T2*64   = 2,097,152
    float* Cb   = Bb    + T2*64;                // T2*64   = 2,097,152
    float* mh   = Cb    + T2*64;                // 16384*256 = 4,194,304
    float* mv   = mh    + (long)16384*256;      // 16384*256 = 4,194,304
    float* cats = xsb;                          // alias (dead after scans): 8192*512
    float* cati = xsb   + (long)8192*512;       // alias: 8192*512

    for (int bi = 0; bi < 2; ++bi) {
        int Bs   = (bi == 0) ? 128 : 256;
        int Lint = (bi == 0) ? 128 : 64;
        prep_k<<<dim3(16384), dim3(64), 0, stream>>>(sem, inst, xbuf, bi);

        for (int l = 0; l < 2; ++l) {
            long slOff = (long)(bi*2)*2 + l;    // flat (stack0_of_bicms, layer l) index

            // h = LN(x)
            ln_k<<<dim3(32768), dim3(64), 0, stream>>>(
                xbuf, hbuf, lns + slOff*256, lnb + slOff*256, 512, 16384);

            // xs = silu(h @ Wx)
            gemm_k<<<dim3(256, 8, 2), dim3(256), 0, stream>>>(
                hbuf, nullptr, 256, 256,
                Wx + slOff*256*512, (long)2*256*512,
                xsb, 16384, 256, 512, EPI_SILU,
                nullptr, 0L, nullptr, 0L, nullptr, 0L);

            // dt = softplus(h @ Wdt + dt_bias)
            gemm_k<<<dim3(256, 8, 2), dim3(256), 0, stream>>>(
                hbuf, nullptr, 256, 256,
                Wdt + slOff*256*512, (long)2*256*512,
                ydt, 16384, 256, 512, EPI_SOFTPLUS,
                dtb + slOff*512, 1024L, nullptr, 0L, nullptr, 0L);

            // Bm = h @ WB ;  Cm = h @ WC
            gemm_k<<<dim3(256, 1, 2), dim3(256), 0, stream>>>(
                hbuf, nullptr, 256, 256,
                WB + slOff*256*64, (long)2*256*64,
                Bb, 16384, 256, 64, EPI_PLAIN,
                nullptr, 0L, nullptr, 0L, nullptr, 0L);
            gemm_k<<<dim3(256, 1, 2), dim3(256), 0, stream>>>(
                hbuf, nullptr, 256, 256,
                WC + slOff*256*64, (long)2*256*64,
                Cb, 16384, 256, 64, EPI_PLAIN,
                nullptr, 0L, nullptr, 0L, nullptr, 0L);

            // selective scan -> y (in-place over dt)
            scan_k<<<dim3(2*Bs, 2), dim3(256), 0, stream>>>(
                ydt, xsb, Bb, Cb, Alog + slOff*512, 1024L, ydt, Bs, Lint);

            // g = (y + Dskip*xs) * silu(h @ Wz)   (overwrites y)
            gemm_k<<<dim3(256, 8, 2), dim3(256), 0, stream>>>(
                hbuf, nullptr, 256, 256,
                Wz + slOff*256*512, (long)2*256*512,
                ydt, 16384, 256, 512, EPI_ZGATE,
                ydt, 0L, xsb, 0L, Dsk + slOff*512, 1024L);

            // x += g @ Wout
            gemm_k<<<dim3(256, 4, 2), dim3(256), 0, stream>>>(
                ydt, nullptr, 512, 512,
                Wo + slOff*512*256, (long)2*512*256,
                xbuf, 16384, 512, 256, EPI_RESID,
                xbuf, 0L, nullptr, 0L, nullptr, 0L);
        }

        // gate merge: merged = sig([fwd,bwd]@gW+gb)*fwd + (1-.)*bwd
        float* mg = (bi == 0) ? mh : mv;
        gemm_k<<<dim3(256, 4, 1), dim3(256), 0, stream>>>(
            xbuf, xbuf + (long)16384*256, 256, 256,
            gW + (long)bi*512*256, 0L,
            mg, 16384, 512, 256, EPI_GATE,
            xbuf, 0L, xbuf + (long)16384*256, 0L, gb + bi*256, 0L);
    }

    // gather concat rows, final merge GEMMs + LN -> d_out
    gather_k<<<dim3(8192), dim3(64), 0, stream>>>(mh, mv, cats, cati);
    for (int mi = 0; mi < 2; ++mi) {
        const float* cat = (mi == 0) ? cats : cati;
        float* logits = ydt;                    // reuse (dead after gate merges)
        gemm_k<<<dim3(128, 4, 1), dim3(256), 0, stream>>>(
            cat, nullptr, 512, 512,
            mW + (long)mi*512*256, 0L,
            logits, 8192, 512, 256, EPI_BIAS,
            mb + mi*256, 0L, nullptr, 0L, nullptr, 0L);
        ln_k<<<dim3(8192), dim3(64), 0, stream>>>(
            logits, out + (long)mi*2097152, mlns + mi*256, mlnb + mi*256, 0, 8192);
    }
}

// Round 3
// 1935.791 us; speedup vs baseline: 1.7665x; 1.7665x over previous
//
#include <hip/hip_runtime.h>
#include <cstdint>

#define DIMV   256
#define DINNER 512
#define STATE  64

typedef __bf16  bf16x8 __attribute__((ext_vector_type(8)));
typedef float   f32x4  __attribute__((ext_vector_type(4)));

static __device__ __forceinline__ float sigmoidf_(float x){ return 1.f/(1.f+expf(-x)); }
static __device__ __forceinline__ float siluf_(float x){ return x/(1.f+expf(-x)); }
static __device__ __forceinline__ float softplusf_(float x){
    return fmaxf(x,0.f) + log1pf(expf(-fabsf(x)));
}
static __device__ __forceinline__ unsigned short f2bf(float f){
    unsigned int u = __float_as_uint(f);
    unsigned int r = (u + 0x7FFFu + ((u>>16)&1u)) >> 16;
    return (unsigned short)r;
}
static __device__ __forceinline__ float b2f(unsigned short s){
    return __uint_as_float(((unsigned int)s)<<16);
}
static __device__ __forceinline__ void gload16(const void* g, void* l){
    __builtin_amdgcn_global_load_lds(
        (const __attribute__((address_space(1))) void*)g,
        (__attribute__((address_space(3))) void*)l, 16, 0, 0);
}

// ---------------------------------------------------------------------------
// prep: build interleaved sequences (fp32 residual stream) for one bicms.
// ---------------------------------------------------------------------------
__global__ __launch_bounds__(64) void prep_k(const float* __restrict__ sem,
                                             const float* __restrict__ inst,
                                             float* __restrict__ xbuf, int bi)
{
    int u = blockIdx.x;
    int lane = threadIdx.x;
    int t; long n;
    if (bi == 0) {
        int s = u >> 7; t = u & 127;
        int b = s >> 5, r = s & 31; int w = t >> 1;
        n = (long)b*2048 + r*64 + w;
    } else {
        int s = u >> 6; t = u & 63;
        int b = s >> 6, w = s & 63; int hh = t >> 1;
        n = (long)b*2048 + hh*64 + w;
    }
    const float* src = ((t & 1) ? inst : sem) + n*256 + lane*4;
    float4 v = *(const float4*)src;
    *(float4*)(xbuf + (long)u*256 + lane*4) = v;
    *(float4*)(xbuf + ((long)16384 + u)*256 + lane*4) = v;
}

// ---------------------------------------------------------------------------
// LayerNorm over 256 dims, one wave per token. BF16OUT: write bf16 (GEMM A).
// ---------------------------------------------------------------------------
template<bool BF16OUT>
__global__ __launch_bounds__(64) void ln_k(const float* __restrict__ x,
                                           void* __restrict__ outp,
                                           const float* __restrict__ sp,
                                           const float* __restrict__ bp,
                                           int pStride, int tokensPerZ)
{
    long tok = blockIdx.x;
    int z = (int)(tok / tokensPerZ);
    const float* s = sp + (long)z*pStride;
    const float* b = bp + (long)z*pStride;
    int lane = threadIdx.x;
    float4 v = *(const float4*)(x + tok*256 + lane*4);
    float sum = v.x+v.y+v.z+v.w;
    #pragma unroll
    for (int o=32;o>=1;o>>=1) sum += __shfl_xor(sum,o);
    float mu = sum * (1.f/256.f);
    float cx=v.x-mu, cy=v.y-mu, cz=v.z-mu, cw=v.w-mu;
    float vs = cx*cx+cy*cy+cz*cz+cw*cw;
    #pragma unroll
    for (int o=32;o>=1;o>>=1) vs += __shfl_xor(vs,o);
    float r = rsqrtf(vs*(1.f/256.f) + 1e-5f);
    float4 sv = *(const float4*)(s + lane*4);
    float4 bv = *(const float4*)(b + lane*4);
    float o0 = cx*r*sv.x + bv.x;
    float o1 = cy*r*sv.y + bv.y;
    float o2 = cz*r*sv.z + bv.z;
    float o3 = cw*r*sv.w + bv.w;
    if (BF16OUT) {
        ushort4 o4; o4.x=f2bf(o0); o4.y=f2bf(o1); o4.z=f2bf(o2); o4.w=f2bf(o3);
        *(ushort4*)((unsigned short*)outp + tok*256 + lane*4) = o4;
    } else {
        float4 o4; o4.x=o0; o4.y=o1; o4.z=o2; o4.w=o3;
        *(float4*)((float*)outp + tok*256 + lane*4) = o4;
    }
}

// ---------------------------------------------------------------------------
// Weight transpose + fp32->bf16: src [z][K][N] -> dst [z][dRowOff+N][dLd=K]
// ---------------------------------------------------------------------------
__global__ __launch_bounds__(256) void tcvt_k(const float* __restrict__ src,
                                              unsigned short* __restrict__ dst,
                                              int K, int N, long sStride, long dStride,
                                              int dRowOff, int dLd)
{
    __shared__ float t[32][33];
    int z = blockIdx.z;
    int n0 = blockIdx.x<<5, k0 = blockIdx.y<<5;
    int tx = threadIdx.x & 31, ty = threadIdx.x >> 5;
    const float* s = src + (long)z*sStride;
    #pragma unroll
    for (int i=0;i<4;i++) t[ty+8*i][tx] = s[(long)(k0+ty+8*i)*N + n0+tx];
    __syncthreads();
    unsigned short* d = dst + (long)z*dStride;
    #pragma unroll
    for (int i=0;i<4;i++)
        d[(long)(dRowOff + n0 + ty + 8*i)*dLd + k0 + tx] = f2bf(t[tx][ty+8*i]);
}

// ---------------------------------------------------------------------------
// MFMA bf16 GEMM, 128x128 tile, BK=32, 4 waves (2x2), 4x4 fragments/wave.
// A: [z][M][lda] bf16 (split-A at splitK for concat inputs).
// Wt: [z via wStride][N][K] bf16 (pre-transposed weights).
// Epilogues fuse all elementwise ops; fp32 accumulate throughout.
// ---------------------------------------------------------------------------
enum { EPI_SILU=0, EPI_SOFTPLUS=1, EPI_PLAIN=2, EPI_ZGATE=3, EPI_RESID=4, EPI_GATE=5, EPI_BIAS=6 };

template<int MODE>
__global__ __launch_bounds__(256) void mgemm_k(
    const unsigned short* __restrict__ A, const unsigned short* __restrict__ A2,
    int splitK, int lda,
    const unsigned short* __restrict__ Wt, long wStride,
    float* __restrict__ Cf, unsigned short* __restrict__ Cb,
    int M, int K, int N,
    const float* __restrict__ p1, long s1,
    const float* __restrict__ p2,
    const float* __restrict__ p3, long s3,
    const unsigned short* __restrict__ pb)
{
    __shared__ __align__(16) unsigned short As[128*32];
    __shared__ __align__(16) unsigned short Bs[128*32];
    int z = blockIdx.z;
    const unsigned short* Az  = A + (long)z*M*lda;
    const unsigned short* A2z = A2 ? (A2 + (long)z*M*lda) : (const unsigned short*)0;
    const unsigned short* Wz  = Wt + (long)z*wStride;
    int bm = blockIdx.x<<7, bn = blockIdx.y<<7;
    int tid = threadIdx.x, w = tid>>6, lane = tid&63;
    int wm = w>>1, wn = w&1;
    int l15 = lane & 15, l4 = lane >> 4;

    f32x4 acc[4][4];
    #pragma unroll
    for (int i=0;i<4;i++)
        #pragma unroll
        for (int j=0;j<4;j++)
            acc[i][j] = (f32x4){0.f,0.f,0.f,0.f};

    int r4 = lane>>2, c8 = (lane&3)<<3;
    for (int k0 = 0; k0 < K; k0 += 32) {
        const unsigned short* Ab; int kl;
        if (k0 < splitK) { Ab = Az; kl = k0; } else { Ab = A2z; kl = k0 - splitK; }
        if (k0) __syncthreads();
        #pragma unroll
        for (int r = 0; r < 2; ++r) {
            int grp = (r<<2) + w;
            gload16(Ab + (long)(bm + (grp<<4) + r4)*lda + kl + c8, &As[grp<<9]);
        }
        #pragma unroll
        for (int r = 0; r < 2; ++r) {
            int grp = (r<<2) + w;
            gload16(Wz + (long)(bn + (grp<<4) + r4)*K + k0 + c8, &Bs[grp<<9]);
        }
        __syncthreads();
        bf16x8 a[4], b[4];
        #pragma unroll
        for (int i=0;i<4;i++)
            a[i] = *(const bf16x8*)&As[((wm<<6) + (i<<4) + l15)*32 + (l4<<3)];
        #pragma unroll
        for (int j=0;j<4;j++)
            b[j] = *(const bf16x8*)&Bs[((wn<<6) + (j<<4) + l15)*32 + (l4<<3)];
        #pragma unroll
        for (int i=0;i<4;i++)
            #pragma unroll
            for (int j=0;j<4;j++)
                acc[i][j] = __builtin_amdgcn_mfma_f32_16x16x32_bf16(a[i], b[j], acc[i][j], 0, 0, 0);
    }

    #pragma unroll
    for (int i=0;i<4;i++){
        int row0 = bm + (wm<<6) + (i<<4) + (l4<<2);
        #pragma unroll
        for (int j=0;j<4;j++){
            int col = bn + (wn<<6) + (j<<4) + l15;
            #pragma unroll
            for (int t=0;t<4;t++){
                int row = row0 + t;
                long rc = ((long)z*M + row)*(long)N + col;
                float v = acc[i][j][t];
                if (MODE == EPI_SILU) {
                    Cb[rc] = f2bf(siluf_(v));
                } else if (MODE == EPI_SOFTPLUS) {
                    Cf[rc] = softplusf_(v + p1[(long)z*s1 + col]);
                } else if (MODE == EPI_PLAIN) {
                    Cb[rc] = f2bf(v);
                } else if (MODE == EPI_ZGATE) {
                    float o = (p1[rc] + p3[(long)z*s3 + col]*b2f(pb[rc])) * siluf_(v);
                    Cb[rc] = f2bf(o);
                } else if (MODE == EPI_RESID) {
                    float o = p1[rc] + v;
                    Cf[rc] = o; Cb[rc] = f2bf(o);
                } else if (MODE == EPI_GATE) {
                    float g = sigmoidf_(v + p3[col]);
                    long rl = (long)row*N + col;
                    Cb[rc] = f2bf(g*p1[rl] + (1.f-g)*p2[rl]);
                } else { // EPI_BIAS
                    Cf[rc] = v + p1[col];
                }
            }
        }
    }
}

// ---------------------------------------------------------------------------
// Selective scan: dt/y fp32 (y in-place over dt), xs/B/C bf16.
// grid.x = 2*Bs (stack 0 fwd, stack 1 reverse), grid.y = 2 channel halves.
// ---------------------------------------------------------------------------
__global__ __launch_bounds__(256) void scan_k(
    const float* __restrict__ dt, const unsigned short* __restrict__ xs,
    const unsigned short* __restrict__ BC,
    const float* __restrict__ Alog, long aStride,
    float* __restrict__ y, int Bs, int Lint)
{
    int q = blockIdx.x;
    int stack = q / Bs;
    int seq = q - stack*Bs;
    int d = blockIdx.y*256 + threadIdx.x;
    float Ad = -expf(Alog[(long)stack*aStride + d]);
    long stackOff = (long)stack * 16384;
    __shared__ float BCsh[128];
    float hs[STATE];
    #pragma unroll
    for (int s=0;s<STATE;s++) hs[s] = 0.f;
    for (int it=0; it<Lint; ++it) {
        int t = stack ? (Lint-1-it) : it;
        long tok = stackOff + (long)seq*Lint + t;
        if (threadIdx.x < 128) BCsh[threadIdx.x] = b2f(BC[tok*128 + threadIdx.x]);
        __syncthreads();
        float dv = dt[tok*DINNER + d];
        float xv = b2f(xs[tok*DINNER + d]);
        float wdec = expf(dv * Ad);
        float u  = dv * xv;
        float acc = 0.f;
        const float4* B4 = (const float4*)BCsh;
        const float4* C4 = (const float4*)(BCsh + 64);
        #pragma unroll
        for (int s4=0; s4<STATE/4; ++s4) {
            float4 bv = B4[s4], cv = C4[s4];
            int s0 = 4*s4;
            hs[s0+0] = fmaf(wdec, hs[s0+0], u*bv.x); acc = fmaf(hs[s0+0], cv.x, acc);
            hs[s0+1] = fmaf(wdec, hs[s0+1], u*bv.y); acc = fmaf(hs[s0+1], cv.y, acc);
            hs[s0+2] = fmaf(wdec, hs[s0+2], u*bv.z); acc = fmaf(hs[s0+2], cv.z, acc);
            hs[s0+3] = fmaf(wdec, hs[s0+3], u*bv.w); acc = fmaf(hs[s0+3], cv.w, acc);
        }
        y[tok*DINNER + d] = acc;
        __syncthreads();
    }
}

// ---------------------------------------------------------------------------
// Gather merged rows (bf16) into concat layout for the final merge GEMMs.
// ---------------------------------------------------------------------------
__global__ __launch_bounds__(64) void gather_k(const unsigned short* __restrict__ mh,
                                               const unsigned short* __restrict__ mv,
                                               unsigned short* __restrict__ catsem,
                                               unsigned short* __restrict__ catinst)
{
    int n = blockIdx.x;
    int lane = threadIdx.x;
    int b = n >> 11;
    int rem = n & 2047;
    int r = rem >> 6, w = rem & 63;
    long hrow = ((long)(b*32 + r)*128 + 2*w)*256;
    long vrow = ((long)(b*64 + w)*64  + 2*r)*256;
    ushort4 hsv = *(const ushort4*)(mh + hrow + lane*4);
    ushort4 vsv = *(const ushort4*)(mv + vrow + lane*4);
    ushort4 hiv = *(const ushort4*)(mh + hrow + 256 + lane*4);
    ushort4 viv = *(const ushort4*)(mv + vrow + 256 + lane*4);
    *(ushort4*)(catsem  + (long)n*512 +       lane*4) = hsv;
    *(ushort4*)(catsem  + (long)n*512 + 256 + lane*4) = vsv;
    *(ushort4*)(catinst + (long)n*512 +       lane*4) = hiv;
    *(ushort4*)(catinst + (long)n*512 + 256 + lane*4) = viv;
}

// ---------------------------------------------------------------------------
extern "C" void kernel_launch(void* const* d_in, const int* in_sizes, int n_in,
                              void* d_out, int out_size, void* d_ws, size_t ws_size,
                              hipStream_t stream)
{
    (void)in_sizes; (void)n_in; (void)out_size; (void)ws_size;
    const float* sem  = (const float*)d_in[0];
    const float* inst = (const float*)d_in[1];
    const float* Wx   = (const float*)d_in[2];
    const float* Wz   = (const float*)d_in[3];
    const float* Wdt  = (const float*)d_in[4];
    const float* WB   = (const float*)d_in[5];
    const float* WC   = (const float*)d_in[6];
    const float* Alog = (const float*)d_in[7];
    const float* Dsk  = (const float*)d_in[8];
    const float* dtb  = (const float*)d_in[9];
    const float* Wo   = (const float*)d_in[10];
    const float* lns  = (const float*)d_in[11];
    const float* lnb  = (const float*)d_in[12];
    const float* gW   = (const float*)d_in[13];
    const float* gb   = (const float*)d_in[14];
    const float* mW   = (const float*)d_in[15];
    const float* mb   = (const float*)d_in[16];
    const float* mlns = (const float*)d_in[17];
    const float* mlnb = (const float*)d_in[18];
    float* out = (float*)d_out;

    // ---- workspace layout (bytes; ~228 MB total) ----
    char* base = (char*)d_ws;
    const long T2 = 32768;
    float* xbuf = (float*)base;                         base += T2*256*4;      // fp32 residual (both stacks)
    float* ydt  = (float*)base;                         base += T2*512*4;      // dt -> y (in-place) -> logits
    unsigned short* xsb  = (unsigned short*)base;       base += T2*512*2;      // xs bf16; later cats/cati
    unsigned short* hb16 = (unsigned short*)base;       base += T2*256*2;      // LN output bf16
    unsigned short* gb16 = (unsigned short*)base;       base += T2*512*2;      // gated g bf16
    unsigned short* xb16 = (unsigned short*)base;       base += T2*256*2;      // bf16 residual copy; BCb aliases
    unsigned short* mh   = (unsigned short*)base;       base += (long)16384*256*2;
    unsigned short* mv   = (unsigned short*)base;       base += (long)16384*256*2;
    unsigned short* wxT  = (unsigned short*)base;       base += (long)8*512*256*2;
    unsigned short* wzT  = (unsigned short*)base;       base += (long)8*512*256*2;
    unsigned short* wdtT = (unsigned short*)base;       base += (long)8*512*256*2;
    unsigned short* woT  = (unsigned short*)base;       base += (long)8*256*512*2;
    unsigned short* wbc  = (unsigned short*)base;       base += (long)8*128*256*2;
    unsigned short* gwT  = (unsigned short*)base;       base += (long)2*256*512*2;
    unsigned short* mwT  = (unsigned short*)base;       base += (long)2*256*512*2;
    unsigned short* bcb  = xb16;                        // [32768][128] bf16, dead before xb16 written
    unsigned short* cats = xsb;                         // [8192][512] bf16 (xs dead by then)
    unsigned short* cati = xsb + (long)8192*512;

    dim3 t256(256);
    // ---- weights: transpose + bf16 (once per launch) ----
    tcvt_k<<<dim3(16,8,8), t256, 0, stream>>>(Wx,  wxT, 256, 512, 256L*512, 512L*256, 0, 256);
    tcvt_k<<<dim3(16,8,8), t256, 0, stream>>>(Wz,  wzT, 256, 512, 256L*512, 512L*256, 0, 256);
    tcvt_k<<<dim3(16,8,8), t256, 0, stream>>>(Wdt, wdtT,256, 512, 256L*512, 512L*256, 0, 256);
    tcvt_k<<<dim3(8,16,8), t256, 0, stream>>>(Wo,  woT, 512, 256, 512L*256, 256L*512, 0, 512);
    tcvt_k<<<dim3(2,8,8),  t256, 0, stream>>>(WB,  wbc, 256, 64,  256L*64,  128L*256, 0, 256);
    tcvt_k<<<dim3(2,8,8),  t256, 0, stream>>>(WC,  wbc, 256, 64,  256L*64,  128L*256, 64, 256);
    tcvt_k<<<dim3(8,16,2), t256, 0, stream>>>(gW,  gwT, 512, 256, 512L*256, 256L*512, 0, 512);
    tcvt_k<<<dim3(8,16,2), t256, 0, stream>>>(mW,  mwT, 512, 256, 512L*256, 256L*512, 0, 512);

    for (int bi = 0; bi < 2; ++bi) {
        int Bs   = (bi == 0) ? 128 : 256;
        int Lint = (bi == 0) ? 128 : 64;
        prep_k<<<dim3(16384), dim3(64), 0, stream>>>(sem, inst, xbuf, bi);

        for (int l = 0; l < 2; ++l) {
            long slOff = (long)bi*4 + l;        // weight-set base; +2 per z (stack)

            ln_k<true><<<dim3(32768), dim3(64), 0, stream>>>(
                xbuf, hb16, lns + slOff*256, lnb + slOff*256, 512, 16384);

            // xs = silu(h @ Wx) -> bf16
            mgemm_k<EPI_SILU><<<dim3(128,4,2), t256, 0, stream>>>(
                hb16, nullptr, 256, 256, wxT + slOff*131072, 262144L,
                nullptr, xsb, 16384, 256, 512,
                nullptr, 0L, nullptr, nullptr, 0L, nullptr);

            // dt = softplus(h @ Wdt + bias) -> fp32
            mgemm_k<EPI_SOFTPLUS><<<dim3(128,4,2), t256, 0, stream>>>(
                hb16, nullptr, 256, 256, wdtT + slOff*131072, 262144L,
                ydt, nullptr, 16384, 256, 512,
                dtb + slOff*512, 1024L, nullptr, nullptr, 0L, nullptr);

            // [B|C] = h @ [WB|WC] -> bf16 packed N=128
            mgemm_k<EPI_PLAIN><<<dim3(128,1,2), t256, 0, stream>>>(
                hb16, nullptr, 256, 256, wbc + slOff*32768, 65536L,
                nullptr, bcb, 16384, 256, 128,
                nullptr, 0L, nullptr, nullptr, 0L, nullptr);

            // selective scan -> y (in-place over dt)
            scan_k<<<dim3(2*Bs,2), t256, 0, stream>>>(
                ydt, xsb, bcb, Alog + slOff*512, 1024L, ydt, Bs, Lint);

            // g = (y + Dskip*xs) * silu(h @ Wz) -> bf16
            mgemm_k<EPI_ZGATE><<<dim3(128,4,2), t256, 0, stream>>>(
                hb16, nullptr, 256, 256, wzT + slOff*131072, 262144L,
                nullptr, gb16, 16384, 256, 512,
                ydt, 0L, nullptr, Dsk + slOff*512, 1024L, xsb);

            // x += g @ Wout  (fp32 residual + bf16 copy)
            mgemm_k<EPI_RESID><<<dim3(128,2,2), t256, 0, stream>>>(
                gb16, nullptr, 512, 512, woT + slOff*131072, 262144L,
                xbuf, xb16, 16384, 512, 256,
                xbuf, 0L, nullptr, nullptr, 0L, nullptr);
        }

        // gate merge: sig([fwd,bwd]@gW+gb)*fwd + (1-.)*bwd -> bf16 mh/mv
        mgemm_k<EPI_GATE><<<dim3(128,2,1), t256, 0, stream>>>(
            xb16, xb16 + (long)16384*256, 256, 256, gwT + (long)bi*131072, 0L,
            nullptr, (bi ? mv : mh), 16384, 512, 256,
            xbuf, 0L, xbuf + (long)16384*256, gb + bi*256, 0L, nullptr);
    }

    // gather concat rows; final merge GEMMs + LN -> d_out
    gather_k<<<dim3(8192), dim3(64), 0, stream>>>(mh, mv, cats, cati);
    for (int mi = 0; mi < 2; ++mi) {
        const unsigned short* cat = (mi == 0) ? cats : cati;
        mgemm_k<EPI_BIAS><<<dim3(64,2,1), t256, 0, stream>>>(
            cat, nullptr, 512, 512, mwT + (long)mi*131072, 0L,
            ydt, nullptr, 8192, 512, 256,
            mb + mi*256, 0L, nullptr, nullptr, 0L, nullptr);
        ln_k<false><<<dim3(8192), dim3(64), 0, stream>>>(
            ydt, out + (long)mi*2097152, mlns + mi*256, mlnb + mi*256, 0, 8192);
    }
}